// Round 2
// baseline (1492.375 us; speedup 1.0000x reference)
//
#include <hip/hip_runtime.h>

#define NN 100000
#define EE 1600000
#define EPSV 1e-5f

// ---------------- degree / normalization ----------------
__global__ void deg_kernel(const int* __restrict__ dst, float* __restrict__ deg) {
    int e = blockIdx.x * 256 + threadIdx.x;
    if (e < EE) atomicAdd(&deg[dst[e]], 1.0f);
}

__global__ void dinv_kernel(float* deg) {
    int n = blockIdx.x * 256 + threadIdx.x;
    if (n < NN) deg[n] = rsqrtf(deg[n] + 1.0f);
}

// ---------------- input projection: h = relu(x @ W_in + b_in) ----------------
__global__ void input_proj(const float* __restrict__ x, const float* __restrict__ Win,
                           const float* __restrict__ bin, float* __restrict__ h) {
    __shared__ float Ws[320];
    __shared__ float bs[64];
    int t = threadIdx.x;
    for (int i = t; i < 320; i += 256) Ws[i] = Win[i];   // FIX: 320 > blockDim, must stride
    if (t < 64) bs[t] = bin[t];
    __syncthreads();
    int n = blockIdx.x * 4 + (t >> 6);
    int c = t & 63;
    if (n >= NN) return;
    float acc = bs[c];
#pragma unroll
    for (int k = 0; k < 5; ++k) acc += x[n * 5 + k] * Ws[k * 64 + c];
    h[n * 64 + c] = fmaxf(acc, 0.f);
}

// ---------------- hw = h @ W (64x64), tiled in LDS ----------------
__global__ __launch_bounds__(256) void gemm64(const float* __restrict__ h,
                                              const float* __restrict__ W,
                                              float* __restrict__ out) {
    __shared__ __align__(16) float Ws[4096];
    __shared__ float Hs[64 * 65];  // +1 pad to break 4-way bank conflict
    int t = threadIdx.x;
    for (int i = t; i < 4096; i += 256) Ws[i] = W[i];
    int base = blockIdx.x * 64;
    for (int i = t; i < 4096; i += 256) {
        int r = i >> 6, c = i & 63;
        Hs[r * 65 + c] = (base + r < NN) ? h[(base + r) * 64 + c] : 0.f;
    }
    __syncthreads();
    int c0 = (t & 15) * 4;
    int r0 = (t >> 4) * 4;
    float acc[4][4] = {};
    for (int k = 0; k < 64; ++k) {
        float4 w = *(const float4*)&Ws[k * 64 + c0];
        float hv[4];
#pragma unroll
        for (int j = 0; j < 4; ++j) hv[j] = Hs[(r0 + j) * 65 + k];
#pragma unroll
        for (int j = 0; j < 4; ++j) {
            acc[j][0] += hv[j] * w.x;
            acc[j][1] += hv[j] * w.y;
            acc[j][2] += hv[j] * w.z;
            acc[j][3] += hv[j] * w.w;
        }
    }
#pragma unroll
    for (int j = 0; j < 4; ++j) {
        int n = base + r0 + j;
        if (n < NN) {
            float4 v = make_float4(acc[j][0], acc[j][1], acc[j][2], acc[j][3]);
            *(float4*)&out[n * 64 + c0] = v;
        }
    }
}

// ---------------- agg init: agg = hw * self_coef + conv_b ----------------
__global__ void init_agg(const float* __restrict__ hw, const float* __restrict__ dinv,
                         const float* __restrict__ b, float* __restrict__ agg) {
    int idx = blockIdx.x * 256 + threadIdx.x;
    if (idx >= NN * 64) return;
    int n = idx >> 6, c = idx & 63;
    float di = dinv[n];
    agg[idx] = hw[idx] * (di * di) + b[c];
}

// ---------------- per-edge scatter-add: 1 wave = 1 edge, lane = channel -------
__global__ void scatter_kernel(const float* __restrict__ hw, const int* __restrict__ src,
                               const int* __restrict__ dst, const float* __restrict__ dinv,
                               float* __restrict__ agg) {
    int e = blockIdx.x * 4 + (threadIdx.x >> 6);
    if (e >= EE) return;
    int c = threadIdx.x & 63;
    int s = src[e], d = dst[e];
    float coef = dinv[s] * dinv[d];
    atomicAdd(&agg[d * 64 + c], hw[s * 64 + c] * coef);
}

// ---------------- BN stats: per-channel sum & sumsq ----------------
__global__ void bn_stats(const float* __restrict__ agg, float* __restrict__ stats) {
    int c = threadIdx.x & 63, g = threadIdx.x >> 6;  // 4 node-groups
    float s = 0.f, ss = 0.f;
    for (int n = blockIdx.x * 4 + g; n < NN; n += gridDim.x * 4) {
        float v = agg[n * 64 + c];
        s += v;
        ss += v * v;
    }
    __shared__ float red[2][4][64];
    red[0][g][c] = s;
    red[1][g][c] = ss;
    __syncthreads();
    if (g == 0) {
        s = red[0][0][c] + red[0][1][c] + red[0][2][c] + red[0][3][c];
        ss = red[1][0][c] + red[1][1][c] + red[1][2][c] + red[1][3][c];
        atomicAdd(&stats[c], s);
        atomicAdd(&stats[64 + c], ss);
    }
}

// ---------------- BN apply + ReLU -> h ----------------
__global__ void bn_apply(const float* __restrict__ agg, const float* __restrict__ stats,
                         const float* __restrict__ gamma, const float* __restrict__ beta,
                         float* __restrict__ h) {
    int idx = blockIdx.x * 256 + threadIdx.x;
    if (idx >= NN * 64) return;
    int c = idx & 63;
    const float invN = 1.0f / (float)NN;
    float mean = stats[c] * invN;
    float var = stats[64 + c] * invN - mean * mean;
    float v = (agg[idx] - mean) * rsqrtf(var + EPSV);
    v = gamma[c] * v + beta[c];
    h[idx] = fmaxf(v, 0.f);
}

// ---------------- classifier: relu(h@W1+b1)@W2 + b2 ----------------
__global__ __launch_bounds__(256) void classifier(const float* __restrict__ h,
                                                  const float* __restrict__ W1,
                                                  const float* __restrict__ b1,
                                                  const float* __restrict__ W2,
                                                  const float* __restrict__ b2,
                                                  float* __restrict__ out) {
    __shared__ float W1s[2048];
    __shared__ float b1s[32];
    __shared__ float W2s[32];
    int t = threadIdx.x;
    for (int i = t; i < 2048; i += 256) W1s[i] = W1[i];
    if (t < 32) {
        b1s[t] = b1[t];
        W2s[t] = W2[t];
    }
    __syncthreads();
    int n = blockIdx.x * 256 + t;
    if (n >= NN) return;
    float4 h4[16];
    const float4* hp = (const float4*)(h + n * 64);
#pragma unroll
    for (int i = 0; i < 16; ++i) h4[i] = hp[i];
    const float* hr = (const float*)h4;
    float o = b2[0];
    for (int c = 0; c < 32; ++c) {
        float z = b1s[c];
#pragma unroll
        for (int k = 0; k < 64; ++k) z += hr[k] * W1s[k * 32 + c];
        o += fmaxf(z, 0.f) * W2s[c];
    }
    out[n] = o;
}

extern "C" void kernel_launch(void* const* d_in, const int* in_sizes, int n_in,
                              void* d_out, int out_size, void* d_ws, size_t ws_size,
                              hipStream_t stream) {
    const float* x    = (const float*)d_in[0];
    const int*   ei   = (const int*)d_in[1];
    const float* Win  = (const float*)d_in[2];
    const float* bin  = (const float*)d_in[3];
    const float* cW   = (const float*)d_in[4];
    const float* cb   = (const float*)d_in[5];
    const float* gam  = (const float*)d_in[6];
    const float* bet  = (const float*)d_in[7];
    const float* W1   = (const float*)d_in[8];
    const float* b1   = (const float*)d_in[9];
    const float* W2   = (const float*)d_in[10];
    const float* b2   = (const float*)d_in[11];
    float* out = (float*)d_out;

    float* h     = (float*)d_ws;          // N*64
    float* hw    = h + NN * 64;           // N*64
    float* agg   = hw + NN * 64;          // N*64
    float* dinv  = agg + NN * 64;         // N (deg, then deg^-1/2 in place)
    float* stats = dinv + NN;             // 3 * 128

    const int* src = ei;
    const int* dst = ei + EE;

    // zero deg + all 3 layers' stats in one memset
    hipMemsetAsync(dinv, 0, (NN + 3 * 128) * sizeof(float), stream);

    deg_kernel<<<(EE + 255) / 256, 256, 0, stream>>>(dst, dinv);
    dinv_kernel<<<(NN + 255) / 256, 256, 0, stream>>>(dinv);
    input_proj<<<(NN + 3) / 4, 256, 0, stream>>>(x, Win, bin, h);

    for (int i = 0; i < 3; ++i) {
        gemm64<<<(NN + 63) / 64, 256, 0, stream>>>(h, cW + i * 4096, hw);
        init_agg<<<(NN * 64 + 255) / 256, 256, 0, stream>>>(hw, dinv, cb + i * 64, agg);
        scatter_kernel<<<(EE + 3) / 4, 256, 0, stream>>>(hw, src, dst, dinv, agg);
        bn_stats<<<256, 256, 0, stream>>>(agg, stats + i * 128);
        bn_apply<<<(NN * 64 + 255) / 256, 256, 0, stream>>>(agg, stats + i * 128,
                                                            gam + i * 64, bet + i * 64, h);
    }

    classifier<<<(NN + 255) / 256, 256, 0, stream>>>(h, W1, b1, W2, b2, out);
}

// Round 3
// 669.666 us; speedup vs baseline: 2.2285x; 2.2285x over previous
//
#include <hip/hip_runtime.h>

#define NN 100000
#define EE 1600000
#define EPSV 1e-5f

// ================= degree histogram (int) =================
__global__ void deg_kernel(const int* __restrict__ dst, int* __restrict__ degi) {
    int e = blockIdx.x * 256 + threadIdx.x;
    if (e < EE) atomicAdd(&degi[dst[e]], 1);
}

__global__ void dinv_kernel(const int* __restrict__ degi, float* __restrict__ dinv) {
    int n = blockIdx.x * 256 + threadIdx.x;
    if (n < NN) dinv[n] = rsqrtf((float)degi[n] + 1.0f);
}

// ================= 2-level exclusive scan over degi -> offsets =================
__global__ void scan1(const int* __restrict__ degi, int* __restrict__ offsets,
                      int* __restrict__ partial) {
    __shared__ int sdata[256];
    int t = threadIdx.x;
    int n = blockIdx.x * 256 + t;
    int v = (n < NN) ? degi[n] : 0;
    sdata[t] = v;
    __syncthreads();
    for (int off = 1; off < 256; off <<= 1) {
        int x = (t >= off) ? sdata[t - off] : 0;
        __syncthreads();
        sdata[t] += x;
        __syncthreads();
    }
    if (n < NN) offsets[n] = sdata[t] - v;  // exclusive
    if (t == 255) partial[blockIdx.x] = sdata[255];
}

__global__ void scan2(int* __restrict__ partial, int* __restrict__ partial_pref, int nparts) {
    __shared__ int sdata[512];
    int t = threadIdx.x;
    int v = (t < nparts) ? partial[t] : 0;
    sdata[t] = v;
    __syncthreads();
    for (int off = 1; off < 512; off <<= 1) {
        int x = (t >= off) ? sdata[t - off] : 0;
        __syncthreads();
        sdata[t] += x;
        __syncthreads();
    }
    if (t < nparts) partial_pref[t] = sdata[t] - v;  // exclusive
}

__global__ void scan3(int* __restrict__ offsets, const int* __restrict__ partial_pref) {
    int n = blockIdx.x * 256 + threadIdx.x;
    if (n < NN) offsets[n] += partial_pref[n >> 8];
}

// ================= CSR fill: counting-sort edges by dst =================
__global__ void fill_kernel(const int* __restrict__ src, const int* __restrict__ dst,
                            const int* __restrict__ offsets, int* __restrict__ cursor,
                            const float* __restrict__ dinv,
                            int* __restrict__ sorted_src, float* __restrict__ sorted_coef) {
    int e = blockIdx.x * 256 + threadIdx.x;
    if (e >= EE) return;
    int s = src[e], d = dst[e];
    int pos = atomicAdd(&cursor[d], 1);
    int idx = offsets[d] + pos;
    sorted_src[idx] = s;
    sorted_coef[idx] = dinv[s] * dinv[d];
}

// ================= input projection: h = relu(x @ W_in + b_in) =================
__global__ void input_proj(const float* __restrict__ x, const float* __restrict__ Win,
                           const float* __restrict__ bin, float* __restrict__ h) {
    __shared__ float Ws[320];
    __shared__ float bs[64];
    int t = threadIdx.x;
    for (int i = t; i < 320; i += 256) Ws[i] = Win[i];
    if (t < 64) bs[t] = bin[t];
    __syncthreads();
    int n = blockIdx.x * 4 + (t >> 6);
    int c = t & 63;
    if (n >= NN) return;
    float acc = bs[c];
#pragma unroll
    for (int k = 0; k < 5; ++k) acc += x[n * 5 + k] * Ws[k * 64 + c];
    h[n * 64 + c] = fmaxf(acc, 0.f);
}

// ================= hw = h @ W (64x64), tiled in LDS =================
__global__ __launch_bounds__(256) void gemm64(const float* __restrict__ h,
                                              const float* __restrict__ W,
                                              float* __restrict__ out) {
    __shared__ __align__(16) float Ws[4096];
    __shared__ float Hs[64 * 65];
    int t = threadIdx.x;
    for (int i = t; i < 4096; i += 256) Ws[i] = W[i];
    int base = blockIdx.x * 64;
    for (int i = t; i < 4096; i += 256) {
        int r = i >> 6, c = i & 63;
        Hs[r * 65 + c] = (base + r < NN) ? h[(base + r) * 64 + c] : 0.f;
    }
    __syncthreads();
    int c0 = (t & 15) * 4;
    int r0 = (t >> 4) * 4;
    float acc[4][4] = {};
    for (int k = 0; k < 64; ++k) {
        float4 w = *(const float4*)&Ws[k * 64 + c0];
        float hv[4];
#pragma unroll
        for (int j = 0; j < 4; ++j) hv[j] = Hs[(r0 + j) * 65 + k];
#pragma unroll
        for (int j = 0; j < 4; ++j) {
            acc[j][0] += hv[j] * w.x;
            acc[j][1] += hv[j] * w.y;
            acc[j][2] += hv[j] * w.z;
            acc[j][3] += hv[j] * w.w;
        }
    }
#pragma unroll
    for (int j = 0; j < 4; ++j) {
        int n = base + r0 + j;
        if (n < NN) {
            float4 v = make_float4(acc[j][0], acc[j][1], acc[j][2], acc[j][3]);
            *(float4*)&out[n * 64 + c0] = v;
        }
    }
}

// ================= CSR gather aggregation (fused agg-init) =================
// agg[n,c] = hw[n,c]*dinv[n]^2 + b[c] + sum_j hw[src_j,c]*coef_j
// one wave per node, lane = channel
__global__ __launch_bounds__(256) void agg_kernel(const float* __restrict__ hw,
                                                  const int* __restrict__ sorted_src,
                                                  const float* __restrict__ sorted_coef,
                                                  const int* __restrict__ offsets,
                                                  const int* __restrict__ degi,
                                                  const float* __restrict__ dinv,
                                                  const float* __restrict__ b,
                                                  float* __restrict__ agg) {
    int t = threadIdx.x;
    int n = blockIdx.x * 4 + (t >> 6);
    if (n >= NN) return;
    int c = t & 63;
    int start = offsets[n];
    int cnt = degi[n];
    float di = dinv[n];
    float acc = hw[n * 64 + c] * (di * di) + b[c];
    for (int base = 0; base < cnt; base += 64) {
        int m = min(64, cnt - base);
        int sv = 0;
        float cv = 0.f;
        if (c < m) {
            sv = sorted_src[start + base + c];
            cv = sorted_coef[start + base + c];
        }
        int k = 0;
        for (; k + 4 <= m; k += 4) {
            int s0 = __shfl(sv, k);
            int s1 = __shfl(sv, k + 1);
            int s2 = __shfl(sv, k + 2);
            int s3 = __shfl(sv, k + 3);
            float c0 = __shfl(cv, k);
            float c1 = __shfl(cv, k + 1);
            float c2 = __shfl(cv, k + 2);
            float c3 = __shfl(cv, k + 3);
            float v0 = hw[s0 * 64 + c];
            float v1 = hw[s1 * 64 + c];
            float v2 = hw[s2 * 64 + c];
            float v3 = hw[s3 * 64 + c];
            acc += v0 * c0;
            acc += v1 * c1;
            acc += v2 * c2;
            acc += v3 * c3;
        }
        for (; k < m; ++k) {
            int s = __shfl(sv, k);
            float cf = __shfl(cv, k);
            acc += hw[s * 64 + c] * cf;
        }
    }
    agg[n * 64 + c] = acc;
}

// ================= BN stats: per-channel sum & sumsq =================
__global__ void bn_stats(const float* __restrict__ agg, float* __restrict__ stats) {
    int c = threadIdx.x & 63, g = threadIdx.x >> 6;
    float s = 0.f, ss = 0.f;
    for (int n = blockIdx.x * 4 + g; n < NN; n += gridDim.x * 4) {
        float v = agg[n * 64 + c];
        s += v;
        ss += v * v;
    }
    __shared__ float red[2][4][64];
    red[0][g][c] = s;
    red[1][g][c] = ss;
    __syncthreads();
    if (g == 0) {
        s = red[0][0][c] + red[0][1][c] + red[0][2][c] + red[0][3][c];
        ss = red[1][0][c] + red[1][1][c] + red[1][2][c] + red[1][3][c];
        atomicAdd(&stats[c], s);
        atomicAdd(&stats[64 + c], ss);
    }
}

// ================= BN apply + ReLU -> h =================
__global__ void bn_apply(const float* __restrict__ agg, const float* __restrict__ stats,
                         const float* __restrict__ gamma, const float* __restrict__ beta,
                         float* __restrict__ h) {
    int idx = blockIdx.x * 256 + threadIdx.x;
    if (idx >= NN * 64) return;
    int c = idx & 63;
    const float invN = 1.0f / (float)NN;
    float mean = stats[c] * invN;
    float var = stats[64 + c] * invN - mean * mean;
    float v = (agg[idx] - mean) * rsqrtf(var + EPSV);
    v = gamma[c] * v + beta[c];
    h[idx] = fmaxf(v, 0.f);
}

// ================= classifier: relu(h@W1+b1)@W2 + b2 =================
__global__ __launch_bounds__(256) void classifier(const float* __restrict__ h,
                                                  const float* __restrict__ W1,
                                                  const float* __restrict__ b1,
                                                  const float* __restrict__ W2,
                                                  const float* __restrict__ b2,
                                                  float* __restrict__ out) {
    __shared__ float W1s[2048];
    __shared__ float b1s[32];
    __shared__ float W2s[32];
    int t = threadIdx.x;
    for (int i = t; i < 2048; i += 256) W1s[i] = W1[i];
    if (t < 32) {
        b1s[t] = b1[t];
        W2s[t] = W2[t];
    }
    __syncthreads();
    int n = blockIdx.x * 256 + t;
    if (n >= NN) return;
    float4 h4[16];
    const float4* hp = (const float4*)(h + n * 64);
#pragma unroll
    for (int i = 0; i < 16; ++i) h4[i] = hp[i];
    const float* hr = (const float*)h4;
    float o = b2[0];
    for (int c = 0; c < 32; ++c) {
        float z = b1s[c];
#pragma unroll
        for (int k = 0; k < 64; ++k) z += hr[k] * W1s[k * 32 + c];
        o += fmaxf(z, 0.f) * W2s[c];
    }
    out[n] = o;
}

extern "C" void kernel_launch(void* const* d_in, const int* in_sizes, int n_in,
                              void* d_out, int out_size, void* d_ws, size_t ws_size,
                              hipStream_t stream) {
    const float* x    = (const float*)d_in[0];
    const int*   ei   = (const int*)d_in[1];
    const float* Win  = (const float*)d_in[2];
    const float* bin  = (const float*)d_in[3];
    const float* cW   = (const float*)d_in[4];
    const float* cb   = (const float*)d_in[5];
    const float* gam  = (const float*)d_in[6];
    const float* bet  = (const float*)d_in[7];
    const float* W1   = (const float*)d_in[8];
    const float* b1   = (const float*)d_in[9];
    const float* W2   = (const float*)d_in[10];
    const float* b2   = (const float*)d_in[11];
    float* out = (float*)d_out;

    // ---- workspace layout (floats unless noted) ----
    float* h     = (float*)d_ws;          // NN*64
    float* hw    = h + NN * 64;           // NN*64
    float* agg   = hw + NN * 64;          // NN*64 (pre-layers: scan temps + cursor alias here)
    float* dinv  = agg + NN * 64;         // NN
    float* stats = dinv + NN;             // 3*128
    int*  degi        = (int*)(stats + 3 * 128);  // NN
    int*  offsets     = degi + NN;                // NN
    int*  sorted_src  = offsets + NN;             // EE
    float* sorted_coef = (float*)(sorted_src + EE); // EE

    // scan temporaries + cursor aliased into agg (unused until layer loop)
    int* cursor       = (int*)agg;            // NN
    int* partial      = (int*)agg + NN;       // 512
    int* partial_pref = (int*)agg + NN + 512; // 512

    const int* src = ei;
    const int* dst = ei + EE;

    const int NB = (NN + 255) / 256;  // 391 scan blocks

    hipMemsetAsync(degi, 0, NN * sizeof(int), stream);
    hipMemsetAsync(cursor, 0, NN * sizeof(int), stream);
    hipMemsetAsync(stats, 0, 3 * 128 * sizeof(float), stream);

    deg_kernel<<<(EE + 255) / 256, 256, 0, stream>>>(dst, degi);
    dinv_kernel<<<NB, 256, 0, stream>>>(degi, dinv);
    scan1<<<NB, 256, 0, stream>>>(degi, offsets, partial);
    scan2<<<1, 512, 0, stream>>>(partial, partial_pref, NB);
    scan3<<<NB, 256, 0, stream>>>(offsets, partial_pref);
    fill_kernel<<<(EE + 255) / 256, 256, 0, stream>>>(src, dst, offsets, cursor, dinv,
                                                      sorted_src, sorted_coef);
    input_proj<<<(NN + 3) / 4, 256, 0, stream>>>(x, Win, bin, h);

    for (int i = 0; i < 3; ++i) {
        gemm64<<<(NN + 63) / 64, 256, 0, stream>>>(h, cW + i * 4096, hw);
        agg_kernel<<<(NN + 3) / 4, 256, 0, stream>>>(hw, sorted_src, sorted_coef,
                                                     offsets, degi, dinv, cb + i * 64, agg);
        bn_stats<<<256, 256, 0, stream>>>(agg, stats + i * 128);
        bn_apply<<<(NN * 64 + 255) / 256, 256, 0, stream>>>(agg, stats + i * 128,
                                                            gam + i * 64, bet + i * 64, h);
    }

    classifier<<<(NN + 255) / 256, 256, 0, stream>>>(h, W1, b1, W2, b2, out);
}